// Round 1
// baseline (715.092 us; speedup 1.0000x reference)
//
#include <hip/hip_runtime.h>
#include <hip/hip_bf16.h>

#define BB 8
#define NN 2048
#define CC 320
#define CQ 64

union F4 { float4 v; float f[4]; };

// ---------------------------------------------------------------------------
// Kernel A: fused QKV projection.
// C[16384][448] = X[16384][320] * Wcat^T + bias, routed to Q/K/V buffers.
// Tile 64x64, BK=16, 256 threads, 4x4 per thread.
// grid (7, 256)
// ---------------------------------------------------------------------------
__global__ __launch_bounds__(256) void qkv_proj(
    const float* __restrict__ x,
    const float* __restrict__ Wq, const float* __restrict__ bq,
    const float* __restrict__ Wk, const float* __restrict__ bk,
    const float* __restrict__ Wv, const float* __restrict__ bv,
    float* __restrict__ Qd, float* __restrict__ Kd, float* __restrict__ Vd) {
  __shared__ float Xs[16][64];   // [k][row]
  __shared__ float Ws[16][64];   // [k][col]
  const int tid = threadIdx.x;
  const int tm = tid & 15, tn = tid >> 4;
  const int row0 = blockIdx.y * 64;
  const int col0 = blockIdx.x * 64;
  const int lr = tid >> 2;          // 0..63
  const int lk = (tid & 3) * 4;     // 0,4,8,12

  // resolve which weight matrix this block's loader row comes from
  const int wrow = col0 + lr;
  const float* Wp; int wr;
  if (wrow < 64)       { Wp = Wq; wr = wrow; }
  else if (wrow < 128) { Wp = Wk; wr = wrow - 64; }
  else                 { Wp = Wv; wr = wrow - 128; }

  float acc[4][4] = {};

  for (int kt = 0; kt < CC; kt += 16) {
    F4 xv, wv;
    xv.v = *(const float4*)&x[(size_t)(row0 + lr) * CC + kt + lk];
    wv.v = *(const float4*)&Wp[(size_t)wr * CC + kt + lk];
    __syncthreads();
#pragma unroll
    for (int e = 0; e < 4; ++e) {
      Xs[lk + e][lr] = xv.f[e];
      Ws[lk + e][lr] = wv.f[e];
    }
    __syncthreads();
#pragma unroll
    for (int k = 0; k < 16; ++k) {
      F4 a, b;
      a.v = *(const float4*)&Xs[k][tm * 4];
      b.v = *(const float4*)&Ws[k][tn * 4];
#pragma unroll
      for (int i = 0; i < 4; ++i)
#pragma unroll
        for (int j = 0; j < 4; ++j)
          acc[i][j] = fmaf(a.f[i], b.f[j], acc[i][j]);
    }
  }

#pragma unroll
  for (int i = 0; i < 4; ++i) {
    const int row = row0 + tm * 4 + i;
#pragma unroll
    for (int j = 0; j < 4; ++j) {
      const int col = col0 + tn * 4 + j;
      const float r = acc[i][j];
      if (col < 64)        Qd[(size_t)row * CQ + col] = r + bq[col];
      else if (col < 128)  Kd[(size_t)row * CQ + (col - 64)] = r + bk[col - 64];
      else                 Vd[(size_t)row * CC + (col - 128)] = r + bv[col - 128];
    }
  }
}

// ---------------------------------------------------------------------------
// Kernel B: per-row softmax stats. For each global row r=(b,n):
//   m_r = max_m Q[r]·K[m],  inv_r = 1/sum_m exp(E-m_r)
// Block = 64 rows; loop m in chunks of 64. 4x4 per thread.
// grid 256
// ---------------------------------------------------------------------------
__global__ __launch_bounds__(256) void row_stats(
    const float* __restrict__ Q, const float* __restrict__ K,
    float* __restrict__ rowmax, float* __restrict__ rowinv) {
  __shared__ float Qs[64][64];   // [q][r]
  __shared__ float Ks[64][64];   // [q][m]
  __shared__ float redM[16][64];
  __shared__ float redS[16][64];
  const int tid = threadIdx.x;
  const int tm = tid & 15, tn = tid >> 4;
  const int r0 = blockIdx.x * 64;
  const int b = r0 >> 11;
  const int lr = tid >> 2, lq0 = (tid & 3) * 16;

#pragma unroll
  for (int f = 0; f < 4; ++f) {
    F4 v; v.v = *(const float4*)&Q[(size_t)(r0 + lr) * CQ + lq0 + f * 4];
#pragma unroll
    for (int e = 0; e < 4; ++e) Qs[lq0 + f * 4 + e][lr] = v.f[e];
  }

  float M[4], S[4];
#pragma unroll
  for (int i = 0; i < 4; ++i) { M[i] = -1e30f; S[i] = 0.f; }

  for (int m0 = 0; m0 < NN; m0 += 64) {
    __syncthreads();
#pragma unroll
    for (int f = 0; f < 4; ++f) {
      F4 v; v.v = *(const float4*)&K[(size_t)(b * NN + m0 + lr) * CQ + lq0 + f * 4];
#pragma unroll
      for (int e = 0; e < 4; ++e) Ks[lq0 + f * 4 + e][lr] = v.f[e];
    }
    __syncthreads();
    float e4[4][4] = {};
    for (int q = 0; q < 64; ++q) {
      F4 a, b;
      a.v = *(const float4*)&Qs[q][tm * 4];
      b.v = *(const float4*)&Ks[q][tn * 4];
#pragma unroll
      for (int i = 0; i < 4; ++i)
#pragma unroll
        for (int j = 0; j < 4; ++j)
          e4[i][j] = fmaf(a.f[i], b.f[j], e4[i][j]);
    }
#pragma unroll
    for (int i = 0; i < 4; ++i) {
      float cm = fmaxf(fmaxf(e4[i][0], e4[i][1]), fmaxf(e4[i][2], e4[i][3]));
      float nm = fmaxf(M[i], cm);
      float s = S[i] * __expf(M[i] - nm);
#pragma unroll
      for (int j = 0; j < 4; ++j) s += __expf(e4[i][j] - nm);
      M[i] = nm; S[i] = s;
    }
  }

#pragma unroll
  for (int i = 0; i < 4; ++i) { redM[tn][tm * 4 + i] = M[i]; redS[tn][tm * 4 + i] = S[i]; }
  __syncthreads();
  if (tid < 64) {
    float gm = -1e30f;
#pragma unroll
    for (int p = 0; p < 16; ++p) gm = fmaxf(gm, redM[p][tid]);
    float gs = 0.f;
#pragma unroll
    for (int p = 0; p < 16; ++p) gs += redS[p][tid] * __expf(redM[p][tid] - gm);
    rowmax[r0 + tid] = gm;
    rowinv[r0 + tid] = 1.0f / gs;
  }
}

// ---------------------------------------------------------------------------
// Kernel C: out[b,n,c] = gamma * sum_k P[k,n]*V[k,c] + x[b,n,c]
//   P[k,n] = exp(Q[k]·K[n] - m_k) * inv_k
// Block: one n-tile of 64 rows x all 320 c. Loop k-chunks of 64:
//   recompute E tile (64k x 64n), form P in LDS, accumulate P^T·V over
//   5 c-sub-chunks of 64. grid 256 (b*32 + ntile)
// ---------------------------------------------------------------------------
__global__ __launch_bounds__(256) void attn_out(
    const float* __restrict__ Q, const float* __restrict__ K,
    const float* __restrict__ V,
    const float* __restrict__ rowmax, const float* __restrict__ rowinv,
    const float* __restrict__ x, const float* __restrict__ gamma,
    float* __restrict__ out) {
  __shared__ float Ksn[64][64];  // [q][n]  (K rows of this n-tile, transposed)
  __shared__ float Qsk[64][64];  // [q][k]
  __shared__ float Ps[64][64];   // [k][n]
  __shared__ float Vs[64][64];   // [k][c]
  const int tid = threadIdx.x;
  const int b = blockIdx.x >> 5;
  const int n0 = (blockIdx.x & 31) * 64;
  const int lr = tid >> 2, lq0 = (tid & 3) * 16;
  const int tn = tid & 15;   // n-group (E cols, acc rows)
  const int tk = tid >> 4;   // k-group for E; c-group for acc

#pragma unroll
  for (int f = 0; f < 4; ++f) {
    F4 v; v.v = *(const float4*)&K[(size_t)(b * NN + n0 + lr) * CQ + lq0 + f * 4];
#pragma unroll
    for (int e = 0; e < 4; ++e) Ksn[lq0 + f * 4 + e][lr] = v.f[e];
  }

  float acc[4][20] = {};  // [i->n][s*4+j->c]

  for (int k0 = 0; k0 < NN; k0 += 64) {
    __syncthreads();
#pragma unroll
    for (int f = 0; f < 4; ++f) {
      F4 v; v.v = *(const float4*)&Q[(size_t)(b * NN + k0 + lr) * CQ + lq0 + f * 4];
#pragma unroll
      for (int e = 0; e < 4; ++e) Qsk[lq0 + f * 4 + e][lr] = v.f[e];
    }
    __syncthreads();

    float e4[4][4] = {};   // [i->k][j->n]
    for (int q = 0; q < 64; ++q) {
      F4 a, bb;
      a.v = *(const float4*)&Qsk[q][tk * 4];
      bb.v = *(const float4*)&Ksn[q][tn * 4];
#pragma unroll
      for (int i = 0; i < 4; ++i)
#pragma unroll
        for (int j = 0; j < 4; ++j)
          e4[i][j] = fmaf(a.f[i], bb.f[j], e4[i][j]);
    }
#pragma unroll
    for (int i = 0; i < 4; ++i) {
      const int gk = b * NN + k0 + tk * 4 + i;
      const float m = rowmax[gk];
      const float inv = rowinv[gk];
#pragma unroll
      for (int j = 0; j < 4; ++j)
        Ps[tk * 4 + i][tn * 4 + j] = __expf(e4[i][j] - m) * inv;
    }
    __syncthreads();

#pragma unroll 1
    for (int s = 0; s < 5; ++s) {
      if (s) __syncthreads();
#pragma unroll
      for (int f = 0; f < 4; ++f) {
        float4 v = *(const float4*)&V[(size_t)(b * NN + k0 + lr) * CC + s * 64 + (tid & 3) * 16 + f * 4];
        *(float4*)&Vs[lr][(tid & 3) * 16 + f * 4] = v;
      }
      __syncthreads();
      for (int k = 0; k < 64; ++k) {
        F4 p, vv;
        p.v = *(const float4*)&Ps[k][tn * 4];
        vv.v = *(const float4*)&Vs[k][tk * 4];
#pragma unroll
        for (int i = 0; i < 4; ++i)
#pragma unroll
          for (int j = 0; j < 4; ++j)
            acc[i][s * 4 + j] = fmaf(p.f[i], vv.f[j], acc[i][s * 4 + j]);
      }
    }
  }

  const float g = gamma[0];
#pragma unroll
  for (int i = 0; i < 4; ++i) {
    const int n = n0 + tn * 4 + i;
    const size_t base = ((size_t)b * NN + n) * CC;
#pragma unroll
    for (int s = 0; s < 5; ++s) {
      const int c = s * 64 + tk * 4;
      F4 xv; xv.v = *(const float4*)&x[base + c];
      F4 o;
#pragma unroll
      for (int j = 0; j < 4; ++j) o.f[j] = g * acc[i][s * 4 + j] + xv.f[j];
      *(float4*)&out[base + c] = o.v;
    }
  }
}

extern "C" void kernel_launch(void* const* d_in, const int* in_sizes, int n_in,
                              void* d_out, int out_size, void* d_ws, size_t ws_size,
                              hipStream_t stream) {
  const float* x     = (const float*)d_in[0];
  const float* Wq    = (const float*)d_in[1];
  const float* bq    = (const float*)d_in[2];
  const float* Wk    = (const float*)d_in[3];
  const float* bk    = (const float*)d_in[4];
  const float* Wv    = (const float*)d_in[5];
  const float* bv    = (const float*)d_in[6];
  const float* gamma = (const float*)d_in[7];
  float* out = (float*)d_out;

  float* ws = (float*)d_ws;
  float* Q      = ws;                              // 16384*64
  float* K      = Q + (size_t)BB * NN * CQ;        // 16384*64
  float* V      = K + (size_t)BB * NN * CQ;        // 16384*320
  float* rowmax = V + (size_t)BB * NN * CC;        // 16384
  float* rowinv = rowmax + (size_t)BB * NN;        // 16384

  qkv_proj<<<dim3(7, 256), 256, 0, stream>>>(x, Wq, bq, Wk, bk, Wv, bv, Q, K, V);
  row_stats<<<256, 256, 0, stream>>>(Q, K, rowmax, rowinv);
  attn_out<<<256, 256, 0, stream>>>(Q, K, V, rowmax, rowinv, x, gamma, out);
}

// Round 2
// 139.470 us; speedup vs baseline: 5.1272x; 5.1272x over previous
//
#include <hip/hip_runtime.h>
#include <hip/hip_bf16.h>

#define BB 8
#define NN 2048
#define CC 320
#define CQ 64

typedef __attribute__((ext_vector_type(8)))  short bf16x8;
typedef __attribute__((ext_vector_type(4)))  float f32x4;
typedef __attribute__((ext_vector_type(16))) float f32x16;
typedef __attribute__((ext_vector_type(4)))  unsigned short us4;
typedef __attribute__((ext_vector_type(8)))  unsigned short us8;
typedef unsigned short u16;

static __device__ __forceinline__ u16 f2b(float f) {
  unsigned u = __builtin_bit_cast(unsigned, f);
  unsigned r = (u + 0x7FFFu + ((u >> 16) & 1u)) >> 16;
  return (u16)r;
}

static __device__ __forceinline__ f32x16 zero16() {
  f32x16 v = {0,0,0,0, 0,0,0,0, 0,0,0,0, 0,0,0,0};
  return v;
}
static __device__ __forceinline__ f32x4 zero4() {
  f32x4 v = {0,0,0,0};
  return v;
}

static __device__ __forceinline__ void gll16(const void* g, void* l) {
  __builtin_amdgcn_global_load_lds(
      (const __attribute__((address_space(1))) unsigned int*)g,
      (__attribute__((address_space(3))) unsigned int*)l, 16, 0, 0);
}

// ---------------------------------------------------------------------------
// K0a: x fp32 -> xb bf16. grid 5120 x 256 (exact: 5,242,880 / 4)
// ---------------------------------------------------------------------------
__global__ __launch_bounds__(256) void cvt_x(const float* __restrict__ x,
                                             u16* __restrict__ xb) {
  const size_t i = (size_t)blockIdx.x * 256 + threadIdx.x;
  float4 v = *(const float4*)(x + i * 4);
  us4 o;
  o.x = f2b(v.x); o.y = f2b(v.y); o.z = f2b(v.z); o.w = f2b(v.w);
  *(us4*)(xb + i * 4) = o;
}

// ---------------------------------------------------------------------------
// K0b: Wq/Wk/Wv fp32 -> concat Wb[448][320] bf16. grid 140 x 256 (exact)
// ---------------------------------------------------------------------------
__global__ __launch_bounds__(256) void cvt_w(const float* __restrict__ Wq,
                                             const float* __restrict__ Wk,
                                             const float* __restrict__ Wv,
                                             u16* __restrict__ Wb) {
  const int i = blockIdx.x * 256 + threadIdx.x;  // 0..35839
  const int idx4 = i * 4;
  const int row = idx4 / CC;
  const int col = idx4 - row * CC;
  const float* src = (row < 64) ? (Wq + (size_t)row * CC)
                   : (row < 128) ? (Wk + (size_t)(row - 64) * CC)
                                 : (Wv + (size_t)(row - 128) * CC);
  float4 v = *(const float4*)(src + col);
  us4 o;
  o.x = f2b(v.x); o.y = f2b(v.y); o.z = f2b(v.z); o.w = f2b(v.w);
  *(us4*)(Wb + (size_t)row * CC + col) = o;
}

// ---------------------------------------------------------------------------
// K1: QKV GEMM. D[16384][448] = xb * Wb^T (+bias, routed).
// bf16 MFMA 32x32x16. Block 256 thr = 4 waves; tile 128M x 64N.
// wave = 32 M-rows x 64 N-cols (2 Nt). All operands direct-from-global (L2).
// grid (7, 128)
// ---------------------------------------------------------------------------
__global__ __launch_bounds__(256) void gemm_qkv(
    const u16* __restrict__ xb, const u16* __restrict__ Wb,
    const float* __restrict__ bq, const float* __restrict__ bk,
    const float* __restrict__ bv,
    u16* __restrict__ Qb, u16* __restrict__ Kb, u16* __restrict__ Vtmp) {
  const int tid = threadIdx.x;
  const int lane = tid & 63, wid = tid >> 6;
  const int r = lane & 31, h = lane >> 5;
  const int m0 = blockIdx.y * 128 + wid * 32;
  const int col0 = blockIdx.x * 64;

  f32x16 acc0 = zero16(), acc1 = zero16();
  const u16* xrow = xb + (size_t)(m0 + r) * CC + h * 8;
  const u16* w0 = Wb + (size_t)(col0 + r) * CC + h * 8;
  const u16* w1 = w0 + 32 * CC;

#pragma unroll 4
  for (int ks = 0; ks < 20; ++ks) {
    bf16x8 a  = *(const bf16x8*)(xrow + ks * 16);
    bf16x8 b0 = *(const bf16x8*)(w0 + ks * 16);
    bf16x8 b1 = *(const bf16x8*)(w1 + ks * 16);
    acc0 = __builtin_amdgcn_mfma_f32_32x32x16_bf16(a, b0, acc0, 0, 0, 0);
    acc1 = __builtin_amdgcn_mfma_f32_32x32x16_bf16(a, b1, acc1, 0, 0, 0);
  }

#pragma unroll
  for (int nt = 0; nt < 2; ++nt) {
    const int col = col0 + nt * 32 + r;
    const float bias = (col < 64) ? bq[col] : (col < 128) ? bk[col - 64] : bv[col - 128];
#pragma unroll
    for (int reg = 0; reg < 16; ++reg) {
      const int row = m0 + (reg & 3) + 8 * (reg >> 2) + 4 * h;
      const float v = (nt ? acc1[reg] : acc0[reg]) + bias;
      const u16 s = f2b(v);
      if (col < 64)        Qb[(size_t)row * CQ + col] = s;
      else if (col < 128)  Kb[(size_t)row * CQ + (col - 64)] = s;
      else                 Vtmp[(size_t)row * CC + (col - 128)] = s;
    }
  }
}

// ---------------------------------------------------------------------------
// K2: transpose Vtmp[16384][320] -> Vt[8][320][2048] (bf16). grid (5, 256)
// ---------------------------------------------------------------------------
__global__ __launch_bounds__(256) void vtrans(const u16* __restrict__ Vtmp,
                                              u16* __restrict__ Vt) {
  __shared__ u16 L[64][72];
  const int t = threadIdx.x;
  const int c0 = blockIdx.x * 64;
  const int p0 = blockIdx.y * 64;
  const int b = p0 >> 11;
  const int pr = t >> 3, cc = (t & 7) * 8;
#pragma unroll
  for (int hh = 0; hh < 2; ++hh) {
    const int p = pr + hh * 32;
    us8 v = *(const us8*)(Vtmp + (size_t)(p0 + p) * CC + c0 + cc);
#pragma unroll
    for (int e = 0; e < 8; ++e) L[p][cc + e] = v[e];
  }
  __syncthreads();
  const int cl = t >> 3, pp = (t & 7) * 8;
#pragma unroll
  for (int hh = 0; hh < 2; ++hh) {
    const int c = cl + hh * 32;
    us8 o;
#pragma unroll
    for (int e = 0; e < 8; ++e) o[e] = L[pp + e][c];
    *(us8*)(Vt + (((size_t)(b * CC + c0 + c)) << 11) + (p0 & 2047) + pp) = o;
  }
}

// ---------------------------------------------------------------------------
// K3: row sums. rowinv[r] = 1 / sum_m exp(Q[r]·K[m] - 30).
// Block = 64 rows, 4 waves; each wave covers m-range [wid*512, +512).
// 16x16x32 MFMA; A-frags (Qb rows) held; B-frags direct from global (L2).
// grid 256 (XCD-swizzled: batch = bid&7)
// ---------------------------------------------------------------------------
__global__ __launch_bounds__(256) void row_stats(
    const u16* __restrict__ Qb, const u16* __restrict__ Kb,
    float* __restrict__ rowinv) {
  __shared__ float Sp[4][64];
  const int tid = threadIdx.x;
  const int lane = tid & 63, wid = tid >> 6;
  const int rl = lane & 15, hq = lane >> 4;
  const int bid = blockIdx.x;
  const int batch = bid & 7;
  const int r0g = batch * NN + (bid >> 3) * 64;

  bf16x8 af[4][2];
#pragma unroll
  for (int mt = 0; mt < 4; ++mt)
#pragma unroll
    for (int qs = 0; qs < 2; ++qs)
      af[mt][qs] = *(const bf16x8*)(Qb + (size_t)(r0g + mt * 16 + rl) * CQ + qs * 32 + hq * 8);

  float S[4][4];
#pragma unroll
  for (int mt = 0; mt < 4; ++mt)
#pragma unroll
    for (int rr = 0; rr < 4; ++rr) S[mt][rr] = 0.f;

  const int mstart = batch * NN + wid * 512;
  for (int ms = 0; ms < 32; ++ms) {
    const u16* kr = Kb + (size_t)(mstart + ms * 16 + rl) * CQ + hq * 8;
    bf16x8 b0 = *(const bf16x8*)(kr);
    bf16x8 b1 = *(const bf16x8*)(kr + 32);
#pragma unroll
    for (int mt = 0; mt < 4; ++mt) {
      f32x4 e = zero4();
      e = __builtin_amdgcn_mfma_f32_16x16x32_bf16(af[mt][0], b0, e, 0, 0, 0);
      e = __builtin_amdgcn_mfma_f32_16x16x32_bf16(af[mt][1], b1, e, 0, 0, 0);
#pragma unroll
      for (int rr = 0; rr < 4; ++rr) S[mt][rr] += __expf(e[rr] - 30.f);
    }
  }

#pragma unroll
  for (int d = 1; d < 16; d <<= 1)
#pragma unroll
    for (int mt = 0; mt < 4; ++mt)
#pragma unroll
      for (int rr = 0; rr < 4; ++rr) S[mt][rr] += __shfl_xor(S[mt][rr], d, 64);

  if (rl == 0) {
#pragma unroll
    for (int mt = 0; mt < 4; ++mt)
#pragma unroll
      for (int rr = 0; rr < 4; ++rr) Sp[wid][mt * 16 + hq * 4 + rr] = S[mt][rr];
  }
  __syncthreads();
  if (tid < 64) {
    const float s = Sp[0][tid] + Sp[1][tid] + Sp[2][tid] + Sp[3][tid];
    rowinv[r0g + tid] = 1.0f / s;
  }
}

// ---------------------------------------------------------------------------
// K4: attention output.
// out[b,n,c] = gamma * sum_k P[k,n] V[k,c] + x[b,n,c],
//   P[k,n] = exp(Kb[n]·Qb[k] - 30) * rowinv[k]
// Block = 64 n x 320 c; 4 waves (wn=wid>>1 n-half, wc=wid&1 c-half).
// Per k-tile(64): Et (32x32x16 MFMA, Kb-frags held) -> P -> swizzled LDS Pt;
// V staged via global_load_lds from Vt (pre-swizzled source); PV MFMA.
// grid 256, XCD swizzle batch = bid&7.
// ---------------------------------------------------------------------------
__global__ __launch_bounds__(256) void attn(
    const u16* __restrict__ Qb, const u16* __restrict__ Kb,
    const u16* __restrict__ Vt, const float* __restrict__ rowinv,
    const float* __restrict__ x, const float* __restrict__ gamma,
    float* __restrict__ out) {
  __shared__ __align__(16) u16 PtU[64 * 64];    // swizzled [n][kk]
  __shared__ __align__(16) u16 VsU[320 * 64];   // swizzled [c][kk]
  const int tid = threadIdx.x;
  const int lane = tid & 63, wid = tid >> 6;
  const int wn = wid >> 1, wc = wid & 1;
  const int r = lane & 31, h = lane >> 5;
  const int bid = blockIdx.x;
  const int b = bid & 7;
  const int n0 = (bid >> 3) * 64;

  // held A-frags for Et: Kb rows of this block's n-range
  bf16x8 kf[4];
  {
    const u16* krow = Kb + (size_t)(b * NN + n0 + wn * 32 + r) * CQ + h * 8;
#pragma unroll
    for (int qs = 0; qs < 4; ++qs) kf[qs] = *(const bf16x8*)(krow + qs * 16);
  }

  f32x16 acc[5];
#pragma unroll
  for (int nt = 0; nt < 5; ++nt) acc[nt] = zero16();

  // global_load_lds source precompute: wave stages c-rows [wid*80, +80)
  const int rsub = lane >> 3;
  const int chnk = (lane & 7) ^ rsub;  // c&7 == rsub for every instruction
  const u16* vsrc0 = Vt + (((size_t)(b * CC + wid * 80 + rsub)) << 11) + chnk * 8;
  u16* vdst0 = VsU + wid * 80 * 64;

  const float* rinv = rowinv + b * NN + wc * 32 + r;
  const u16* qrow = Qb + (size_t)(b * NN + wc * 32 + r) * CQ + h * 8;

#pragma unroll 1
  for (int k0 = 0; k0 < NN; k0 += 64) {
    __syncthreads();  // previous PV reads done
    // stage V tile (async)
#pragma unroll
    for (int j = 0; j < 10; ++j)
      gll16(vsrc0 + ((size_t)j << 14) + k0, vdst0 + j * 512);

    // Et = Kb(n) · Qb(k)^T  -> 32x32 tile per wave
    f32x16 e = zero16();
    {
      const u16* q0 = qrow + (size_t)k0 * CQ;
#pragma unroll
      for (int qs = 0; qs < 4; ++qs) {
        bf16x8 qf = *(const bf16x8*)(q0 + qs * 16);
        e = __builtin_amdgcn_mfma_f32_32x32x16_bf16(kf[qs], qf, e, 0, 0, 0);
      }
    }
    const float inv = rinv[k0];
    const int kk = wc * 32 + r;
#pragma unroll
    for (int reg = 0; reg < 16; ++reg) {
      const int nl = wn * 32 + (reg & 3) + 8 * (reg >> 2) + 4 * h;
      const float p = __expf(e[reg] - 30.f) * inv;
      const int byteoff = nl * 128 + ((((kk >> 3) ^ (nl & 7)) << 4)) + (kk & 7) * 2;
      *(u16*)((char*)PtU + byteoff) = f2b(p);
    }

    asm volatile("s_waitcnt vmcnt(0)" ::: "memory");
    __syncthreads();  // Pt written + Vs staged

    // PV: wave = 32 n (wn) x 160 c (wc), K=64 in 4 steps
#pragma unroll
    for (int ks = 0; ks < 4; ++ks) {
      const int ch = ks * 2 + h;
      const int na = wn * 32 + r;
      bf16x8 pa = *(const bf16x8*)((char*)PtU + na * 128 + ((ch ^ (na & 7)) << 4));
#pragma unroll
      for (int nt = 0; nt < 5; ++nt) {
        const int c = wc * 160 + nt * 32 + r;
        bf16x8 vb = *(const bf16x8*)((char*)VsU + c * 128 + ((ch ^ (c & 7)) << 4));
        acc[nt] = __builtin_amdgcn_mfma_f32_32x32x16_bf16(pa, vb, acc[nt], 0, 0, 0);
      }
    }
  }

  const float g = gamma[0];
#pragma unroll
  for (int nt = 0; nt < 5; ++nt) {
#pragma unroll
    for (int reg = 0; reg < 16; ++reg) {
      const int nl = n0 + wn * 32 + (reg & 3) + 8 * (reg >> 2) + 4 * h;
      const int c = wc * 160 + nt * 32 + r;
      const size_t idx = ((size_t)(b * NN) + nl) * CC + c;
      out[idx] = g * acc[nt][reg] + x[idx];
    }
  }
}

extern "C" void kernel_launch(void* const* d_in, const int* in_sizes, int n_in,
                              void* d_out, int out_size, void* d_ws, size_t ws_size,
                              hipStream_t stream) {
  const float* x     = (const float*)d_in[0];
  const float* Wq    = (const float*)d_in[1];
  const float* bq    = (const float*)d_in[2];
  const float* Wk    = (const float*)d_in[3];
  const float* bk    = (const float*)d_in[4];
  const float* Wv    = (const float*)d_in[5];
  const float* bv    = (const float*)d_in[6];
  const float* gamma = (const float*)d_in[7];
  float* out = (float*)d_out;

  char* w = (char*)d_ws;
  u16* xb     = (u16*)(w);                         // 16384*320
  u16* Wb     = (u16*)(w + 10485760);              // 448*320
  u16* Qb     = (u16*)(w + 10772480);              // 16384*64
  u16* Kb     = (u16*)(w + 12869632);              // 16384*64
  u16* Vtmp   = (u16*)(w + 14966784);              // 16384*320
  u16* Vt     = (u16*)(w + 25452544);              // 8*320*2048
  float* rinv = (float*)(w + 35938304);            // 16384

  cvt_x<<<5120, 256, 0, stream>>>(x, xb);
  cvt_w<<<140, 256, 0, stream>>>(Wq, Wk, Wv, Wb);
  gemm_qkv<<<dim3(7, 128), 256, 0, stream>>>(xb, Wb, bq, bk, bv, Qb, Kb, Vtmp);
  vtrans<<<dim3(5, 256), 256, 0, stream>>>(Vtmp, Vt);
  row_stats<<<256, 256, 0, stream>>>(Qb, Kb, rinv);
  attn<<<256, 256, 0, stream>>>(Qb, Kb, Vt, rinv, x, gamma, out);
}